// Round 1
// baseline (1267.119 us; speedup 1.0000x reference)
//
#include <hip/hip_runtime.h>
#include <stdint.h>

#define TOKENS 25088      // 8*56*56
#define EPS_LN 1e-5f
#define PSTR 232          // LDS row stride for Ps/Vt (elems); 232*2B=464B=29*16B aligned

typedef __attribute__((ext_vector_type(8))) short bf16x8;
typedef __attribute__((ext_vector_type(4))) float f32x4;

__device__ __forceinline__ unsigned short f2bf(float f) {
  union { float f; unsigned u; } v; v.f = f;
  unsigned r = v.u + 0x7FFFu + ((v.u >> 16) & 1u);
  return (unsigned short)(r >> 16);
}
__device__ __forceinline__ float bf2f(unsigned short h) {
  union { unsigned u; float f; } v; v.u = ((unsigned)h) << 16;
  return v.f;
}

__device__ __forceinline__ void gload16(const void* g, void* l) {
  __builtin_amdgcn_global_load_lds(
      (const __attribute__((address_space(1))) void*)g,
      (__attribute__((address_space(3))) void*)l, 16, 0, 0);
}

// ---------------- converts ----------------
__global__ __launch_bounds__(256) void k_cvt_x(const float* __restrict__ x,
                                               unsigned short* __restrict__ xb) {
  int i = (blockIdx.x * 256 + threadIdx.x) * 4;
  float4 v = *(const float4*)(x + i);
  unsigned r0 = (unsigned)f2bf(v.x) | ((unsigned)f2bf(v.y) << 16);
  unsigned r1 = (unsigned)f2bf(v.z) | ((unsigned)f2bf(v.w) << 16);
  uint2 o; o.x = r0; o.y = r1;
  *(uint2*)(xb + i) = o;
}

__global__ __launch_bounds__(256) void k_cvt_T(const float* __restrict__ w,
                                               unsigned short* __restrict__ wT,
                                               int R, int C) {
  int i = blockIdx.x * 256 + threadIdx.x;
  if (i < R * C) {
    int r = i / C, c = i - r * C;
    wT[(size_t)c * R + r] = f2bf(w[i]);
  }
}

// ---------------- GEMM mainloop (m97-style 128x128x32, bf16 MFMA) ----------------
__device__ __forceinline__ void gemm_mainloop(
    const unsigned short* __restrict__ A, const unsigned short* __restrict__ BT,
    int K, int row0, int col0,
    unsigned short* As, unsigned short* Bs, f32x4 acc[4][4]) {
  const int tid = threadIdx.x;
  const int lane = tid & 63, wave = tid >> 6;
  const int lr = lane & 15, lg = lane >> 4;
  const int wm = wave >> 1, wn = wave & 1;
  const int c0 = wave * 2, c1 = c0 + 1;
  const int sr0 = c0 * 16 + (lane >> 2), sr1 = c1 * 16 + (lane >> 2);
  const int scc = (lane & 3) * 8;
  const unsigned short* gA0 = A + (size_t)(row0 + sr0) * K + scc;
  const unsigned short* gA1 = A + (size_t)(row0 + sr1) * K + scc;
  const unsigned short* gB0 = BT + (size_t)(col0 + sr0) * K + scc;
  const unsigned short* gB1 = BT + (size_t)(col0 + sr1) * K + scc;
  unsigned short* lA0 = As + c0 * 512;
  unsigned short* lA1 = As + c1 * 512;
  unsigned short* lB0 = Bs + c0 * 512;
  unsigned short* lB1 = Bs + c1 * 512;
  for (int k0 = 0; k0 < K; k0 += 32) {
    __syncthreads();
    gload16(gA0, lA0); gload16(gA1, lA1);
    gload16(gB0, lB0); gload16(gB1, lB1);
    gA0 += 32; gA1 += 32; gB0 += 32; gB1 += 32;
    __syncthreads();
    bf16x8 af[4], bfr[4];
#pragma unroll
    for (int f = 0; f < 4; f++) {
      af[f]  = *(const bf16x8*)(As + (wm * 64 + f * 16 + lr) * 32 + lg * 8);
      bfr[f] = *(const bf16x8*)(Bs + (wn * 64 + f * 16 + lr) * 32 + lg * 8);
    }
#pragma unroll
    for (int i = 0; i < 4; i++)
#pragma unroll
      for (int j = 0; j < 4; j++)
        acc[i][j] = __builtin_amdgcn_mfma_f32_16x16x32_bf16(af[i], bfr[j], acc[i][j], 0, 0, 0);
  }
}

// GEMM1: qkv = x@w_qkv + b, scattered to planes [3*96][56*56][64] bf16
__global__ __launch_bounds__(256) void k_gemm_qkv(
    const unsigned short* __restrict__ A, const unsigned short* __restrict__ BT,
    const float* __restrict__ bias, unsigned short* __restrict__ qkvp) {
  __shared__ unsigned short As[128 * 32];
  __shared__ unsigned short Bs[128 * 32];
  f32x4 acc[4][4];
  f32x4 z0 = {0.f, 0.f, 0.f, 0.f};
#pragma unroll
  for (int i = 0; i < 4; i++)
#pragma unroll
    for (int j = 0; j < 4; j++) acc[i][j] = z0;
  const int row0 = blockIdx.x * 128, col0 = blockIdx.y * 128;
  gemm_mainloop(A, BT, 768, row0, col0, As, Bs, acc);
  const int lane = threadIdx.x & 63, wave = threadIdx.x >> 6;
  const int lr = lane & 15, lg = lane >> 4;
  const int wm = wave >> 1, wn = wave & 1;
#pragma unroll
  for (int j = 0; j < 4; j++) {
    int col = col0 + wn * 64 + j * 16 + lr;
    float bv = bias[col];
    int qkv_idx = col / 768;
    int head = (col >> 6) % 12;
    int d = col & 63;
#pragma unroll
    for (int i = 0; i < 4; i++) {
#pragma unroll
      for (int r = 0; r < 4; r++) {
        int row = row0 + wm * 64 + i * 16 + lg * 4 + r;
        int b = row / 3136, hw = row - b * 3136;
        size_t dst = (((size_t)(qkv_idx * 96 + b * 12 + head)) * 3136 + hw) * 64 + d;
        qkvp[dst] = f2bf(acc[i][j][r] + bv);
      }
    }
  }
}

// GEMM2: out = X2@w_proj + b (fp32 out, row-major)
__global__ __launch_bounds__(256) void k_gemm_proj(
    const unsigned short* __restrict__ A, const unsigned short* __restrict__ BT,
    const float* __restrict__ bias, float* __restrict__ out) {
  __shared__ unsigned short As[128 * 32];
  __shared__ unsigned short Bs[128 * 32];
  f32x4 acc[4][4];
  f32x4 z0 = {0.f, 0.f, 0.f, 0.f};
#pragma unroll
  for (int i = 0; i < 4; i++)
#pragma unroll
    for (int j = 0; j < 4; j++) acc[i][j] = z0;
  const int row0 = blockIdx.x * 128, col0 = blockIdx.y * 128;
  gemm_mainloop(A, BT, 768, row0, col0, As, Bs, acc);
  const int lane = threadIdx.x & 63, wave = threadIdx.x >> 6;
  const int lr = lane & 15, lg = lane >> 4;
  const int wm = wave >> 1, wn = wave & 1;
#pragma unroll
  for (int j = 0; j < 4; j++) {
    int col = col0 + wn * 64 + j * 16 + lr;
    float bv = bias[col];
#pragma unroll
    for (int i = 0; i < 4; i++) {
#pragma unroll
      for (int r = 0; r < 4; r++) {
        int row = row0 + wm * 64 + i * 16 + lg * 4 + r;
        out[(size_t)row * 768 + col] = acc[i][j][r] + bv;
      }
    }
  }
}

// ---------------- depthwise conv3x3 + LayerNorm, write window layout ----------------
__global__ __launch_bounds__(256) void k_conv_ln(
    const unsigned short* __restrict__ qkvp,
    const float* __restrict__ wq, const float* __restrict__ wk, const float* __restrict__ wv,
    const float* __restrict__ gq, const float* __restrict__ bq,
    const float* __restrict__ gk, const float* __restrict__ bk,
    const float* __restrict__ gv, const float* __restrict__ bv,
    unsigned short* __restrict__ qw_, unsigned short* __restrict__ kw_,
    unsigned short* __restrict__ vw_) {
  int wid = blockIdx.x * 4 + (threadIdx.x >> 6);
  int c = threadIdx.x & 63;
  int plane = wid / 3136;
  int hw = wid - plane * 3136;
  int h = hw / 56, w = hw - (hw / 56) * 56;
  int qkv_idx = plane / 96, p96 = plane - qkv_idx * 96;
  const float* wt = qkv_idx == 0 ? wq : (qkv_idx == 1 ? wk : wv);
  const unsigned short* base = qkvp + (size_t)plane * 3136 * 64;
  float acc = 0.f;
#pragma unroll
  for (int dh = -1; dh <= 1; dh++) {
    int hh = h + dh;
    if ((unsigned)hh < 56u) {
#pragma unroll
      for (int dw = -1; dw <= 1; dw++) {
        int ww = w + dw;
        if ((unsigned)ww < 56u) {
          acc += bf2f(base[(hh * 56 + ww) * 64 + c]) * wt[((dh + 1) * 3 + (dw + 1)) * 64 + c];
        }
      }
    }
  }
  float s = acc;
#pragma unroll
  for (int m = 1; m < 64; m <<= 1) s += __shfl_xor(s, m, 64);
  float mean = s * (1.f / 64.f);
  float dv = acc - mean;
  float s2 = dv * dv;
#pragma unroll
  for (int m = 1; m < 64; m <<= 1) s2 += __shfl_xor(s2, m, 64);
  float rstd = rsqrtf(s2 * (1.f / 64.f) + EPS_LN);
  const float* g = qkv_idx == 0 ? gq : (qkv_idx == 1 ? gk : gv);
  const float* bb = qkv_idx == 0 ? bq : (qkv_idx == 1 ? bk : bv);
  float val = dv * rstd * g[c] + bb[c];
  int win = p96 * 16 + (h / 14) * 4 + (w / 14);
  int rowL = (h % 14) * 14 + (w % 14);
  unsigned short* dst = qkv_idx == 0 ? qw_ : (qkv_idx == 1 ? kw_ : vw_);
  dst[((size_t)win * 196 + rowL) * 64 + c] = f2bf(val);
}

// ---------------- window attention ----------------
__global__ __launch_bounds__(256) void k_attn(
    const unsigned short* __restrict__ qw_, const unsigned short* __restrict__ kw_,
    const unsigned short* __restrict__ vw_,
    const float* __restrict__ rph, const float* __restrict__ rpw,
    unsigned short* __restrict__ X2) {
  __shared__ unsigned short Vt[64 * PSTR];   // [c][key] transposed V
  __shared__ unsigned short Ps[64 * PSTR];   // [wave*16+m][key] probabilities
  __shared__ float relh[196 * 14];
  __shared__ float relw[196 * 14];
  const int tid = threadIdx.x;
  const int win = blockIdx.x;
  const size_t woff = (size_t)win * (196 * 64);

  // stage V transposed; zero-pad keys 196..PSTR-1
  for (int i = tid; i < 196 * 64; i += 256) {
    int key = i >> 6, c = i & 63;
    Vt[c * PSTR + key] = vw_[woff + i];
  }
  for (int i = tid; i < 64 * (PSTR - 196); i += 256) {
    int c = i / (PSTR - 196), key = 196 + (i % (PSTR - 196));
    Vt[c * PSTR + key] = 0;
  }
  for (int i = tid; i < 64 * (PSTR - 196); i += 256) {
    int m = i / (PSTR - 196), key = 196 + (i % (PSTR - 196));
    Ps[m * PSTR + key] = 0;
  }
  // decomposed rel-pos bias tables: relh[qi][kh], relw[qi][kw]
  for (int i = tid; i < 196 * 14; i += 256) {
    int qi = i / 14, t = i - (i / 14) * 14;
    int qh = qi / 14, qx = qi - qh * 14;
    const unsigned short* qrow = qw_ + woff + qi * 64;
    const float* rh = rph + (qh - t + 13) * 64;
    const float* rw = rpw + (qx - t + 13) * 64;
    float sh = 0.f, sw = 0.f;
#pragma unroll 16
    for (int c2 = 0; c2 < 64; c2++) {
      float qv = bf2f(qrow[c2]);
      sh += qv * rh[c2];
      sw += qv * rw[c2];
    }
    relh[i] = sh; relw[i] = sw;
  }
  __syncthreads();

  const int lane = tid & 63, wave = tid >> 6;
  const int lr = lane & 15, lg = lane >> 4;
  const float scale = 0.125f;

  for (int mt = wave; mt < 13; mt += 4) {
    int qra = mt * 16 + lr; if (qra > 195) qra = 195;
    bf16x8 qa0 = *(const bf16x8*)(qw_ + woff + qra * 64 + lg * 8);
    bf16x8 qa1 = *(const bf16x8*)(qw_ + woff + qra * 64 + 32 + lg * 8);
    f32x4 sc[13];
#pragma unroll
    for (int nt = 0; nt < 13; nt++) {
      int kr = nt * 16 + lr; if (kr > 195) kr = 195;
      bf16x8 kb0 = *(const bf16x8*)(kw_ + woff + kr * 64 + lg * 8);
      bf16x8 kb1 = *(const bf16x8*)(kw_ + woff + kr * 64 + 32 + lg * 8);
      f32x4 z = {0.f, 0.f, 0.f, 0.f};
      z = __builtin_amdgcn_mfma_f32_16x16x32_bf16(qa0, kb0, z, 0, 0, 0);
      z = __builtin_amdgcn_mfma_f32_16x16x32_bf16(qa1, kb1, z, 0, 0, 0);
      sc[nt] = z;
    }
    const int qr0 = mt * 16 + lg * 4;
    float mx[4] = {-3e38f, -3e38f, -3e38f, -3e38f};
#pragma unroll
    for (int nt = 0; nt < 13; nt++) {
      int col = nt * 16 + lr;
      int ch = col / 14, cw = col - ch * 14;
      bool cv = col < 196;
#pragma unroll
      for (int r = 0; r < 4; r++) {
        float v;
        if (cv) {
          v = sc[nt][r] * scale;
          int q = qr0 + r;
          if (q < 196) v += relh[q * 14 + ch] + relw[q * 14 + cw];
        } else v = -3e38f;
        sc[nt][r] = v;
        mx[r] = fmaxf(mx[r], v);
      }
    }
#pragma unroll
    for (int m = 1; m < 16; m <<= 1)
#pragma unroll
      for (int r = 0; r < 4; r++)
        mx[r] = fmaxf(mx[r], __shfl_xor(mx[r], m, 64));
    float sm[4] = {0.f, 0.f, 0.f, 0.f};
#pragma unroll
    for (int nt = 0; nt < 13; nt++)
#pragma unroll
      for (int r = 0; r < 4; r++) {
        float p = __expf(sc[nt][r] - mx[r]);
        sc[nt][r] = p;
        sm[r] += p;
      }
#pragma unroll
    for (int m = 1; m < 16; m <<= 1)
#pragma unroll
      for (int r = 0; r < 4; r++)
        sm[r] += __shfl_xor(sm[r], m, 64);
    float inv[4];
#pragma unroll
    for (int r = 0; r < 4; r++) inv[r] = 1.f / sm[r];
#pragma unroll
    for (int nt = 0; nt < 13; nt++)
#pragma unroll
      for (int r = 0; r < 4; r++)
        Ps[(wave * 16 + lg * 4 + r) * PSTR + nt * 16 + lr] = f2bf(sc[nt][r] * inv[r]);

    f32x4 o[4];
#pragma unroll
    for (int ct = 0; ct < 4; ct++) o[ct] = (f32x4){0.f, 0.f, 0.f, 0.f};
#pragma unroll
    for (int kt = 0; kt < 7; kt++) {
      bf16x8 pa = *(const bf16x8*)(Ps + (wave * 16 + lr) * PSTR + kt * 32 + lg * 8);
#pragma unroll
      for (int ct = 0; ct < 4; ct++) {
        bf16x8 vb = *(const bf16x8*)(Vt + (ct * 16 + lr) * PSTR + kt * 32 + lg * 8);
        o[ct] = __builtin_amdgcn_mfma_f32_16x16x32_bf16(pa, vb, o[ct], 0, 0, 0);
      }
    }
    // epilogue: +residual (ori_q == Q window), write to [25088][768] bf16
    int p96 = win >> 4, widx = win & 15;
    int wh = widx >> 2, ww = widx & 3;
    int bb = p96 / 12, head = p96 - (p96 / 12) * 12;
#pragma unroll
    for (int ct = 0; ct < 4; ct++) {
      int c = ct * 16 + lr;
#pragma unroll
      for (int r = 0; r < 4; r++) {
        int q = qr0 + r;
        if (q < 196) {
          float val = o[ct][r] + bf2f(qw_[woff + q * 64 + c]);
          int qh = q / 14, qx = q - (q / 14) * 14;
          int hh = wh * 14 + qh, wv = ww * 14 + qx;
          size_t tok = ((size_t)bb * 56 + hh) * 56 + wv;
          X2[tok * 768 + (size_t)head * 64 + c] = f2bf(val);
        }
      }
    }
  }
}

extern "C" void kernel_launch(void* const* d_in, const int* in_sizes, int n_in,
                              void* d_out, int out_size, void* d_ws, size_t ws_size,
                              hipStream_t stream) {
  const float* x      = (const float*)d_in[0];
  const float* w_qkv  = (const float*)d_in[1];
  const float* b_qkv  = (const float*)d_in[2];
  const float* w_proj = (const float*)d_in[3];
  const float* b_proj = (const float*)d_in[4];
  const float* pqw = (const float*)d_in[5];
  const float* pkw = (const float*)d_in[6];
  const float* pvw = (const float*)d_in[7];
  const float* gq = (const float*)d_in[8];
  const float* bq = (const float*)d_in[9];
  const float* gk = (const float*)d_in[10];
  const float* bk = (const float*)d_in[11];
  const float* gv = (const float*)d_in[12];
  const float* bv = (const float*)d_in[13];
  const float* rph = (const float*)d_in[14];
  const float* rpw = (const float*)d_in[15];
  float* out = (float*)d_out;

  char* ws = (char*)d_ws;
  size_t off = 0;
  auto alloc = [&](size_t bytes) {
    void* p = ws + off;
    off = (off + bytes + 255) & ~(size_t)255;
    return p;
  };
  unsigned short* xb   = (unsigned short*)alloc((size_t)TOKENS * 768 * 2);
  unsigned short* wqT  = (unsigned short*)alloc((size_t)2304 * 768 * 2);
  unsigned short* wpT  = (unsigned short*)alloc((size_t)768 * 768 * 2);
  unsigned short* qkvp = (unsigned short*)alloc((size_t)288 * 3136 * 64 * 2);
  unsigned short* qwin = (unsigned short*)alloc((size_t)1536 * 196 * 64 * 2);
  unsigned short* kwin = (unsigned short*)alloc((size_t)1536 * 196 * 64 * 2);
  unsigned short* vwin = (unsigned short*)alloc((size_t)1536 * 196 * 64 * 2);
  unsigned short* X2 = xb;  // alias: xb dead after GEMM1, X2 written by attention

  k_cvt_x<<<dim3(TOKENS * 768 / 1024), dim3(256), 0, stream>>>(x, xb);
  k_cvt_T<<<dim3((768 * 2304 + 255) / 256), dim3(256), 0, stream>>>(w_qkv, wqT, 768, 2304);
  k_cvt_T<<<dim3((768 * 768 + 255) / 256), dim3(256), 0, stream>>>(w_proj, wpT, 768, 768);
  k_gemm_qkv<<<dim3(196, 18), dim3(256), 0, stream>>>(xb, wqT, b_qkv, qkvp);
  k_conv_ln<<<dim3(288 * 3136 / 4), dim3(256), 0, stream>>>(
      qkvp, pqw, pkw, pvw, gq, bq, gk, bk, gv, bv, qwin, kwin, vwin);
  k_attn<<<dim3(1536), dim3(256), 0, stream>>>(qwin, kwin, vwin, rph, rpw, X2);
  k_gemm_proj<<<dim3(196, 6), dim3(256), 0, stream>>>(X2, wpT, b_proj, out);
}

// Round 3
// 1031.374 us; speedup vs baseline: 1.2286x; 1.2286x over previous
//
#include <hip/hip_runtime.h>
#include <stdint.h>

#define TOKENS 25088      // 8*56*56
#define EPS_LN 1e-5f
#define VSTR 232          // Vt stride (elems); 232*2B=464B, 16B-aligned, 2-way-read
#define RSTR 208          // Rt stride (elems) = 13*16 q-columns

typedef __attribute__((ext_vector_type(8))) short bf16x8;
typedef __attribute__((ext_vector_type(4))) float f32x4;

__device__ __forceinline__ unsigned short f2bf(float f) {
  union { float f; unsigned u; } v; v.f = f;
  unsigned r = v.u + 0x7FFFu + ((v.u >> 16) & 1u);
  return (unsigned short)(r >> 16);
}
__device__ __forceinline__ float bf2f(unsigned short h) {
  union { unsigned u; float f; } v; v.u = ((unsigned)h) << 16;
  return v.f;
}
__device__ __forceinline__ unsigned cvt_pk_bf16(float lo, float hi) {
  unsigned r;
  asm("v_cvt_pk_bf16_f32 %0, %1, %2" : "=v"(r) : "v"(lo), "v"(hi));
  return r;
}

__device__ __forceinline__ void gload16(const void* g, void* l) {
  __builtin_amdgcn_global_load_lds(
      (const __attribute__((address_space(1))) void*)g,
      (__attribute__((address_space(3))) void*)l, 16, 0, 0);
}

// ---------------- converts ----------------
__global__ __launch_bounds__(256) void k_cvt_x(const float* __restrict__ x,
                                               unsigned short* __restrict__ xb) {
  int i = (blockIdx.x * 256 + threadIdx.x) * 4;
  float4 v = *(const float4*)(x + i);
  unsigned r0 = (unsigned)f2bf(v.x) | ((unsigned)f2bf(v.y) << 16);
  unsigned r1 = (unsigned)f2bf(v.z) | ((unsigned)f2bf(v.w) << 16);
  uint2 o; o.x = r0; o.y = r1;
  *(uint2*)(xb + i) = o;
}

__global__ __launch_bounds__(256) void k_cvt_T(const float* __restrict__ w,
                                               unsigned short* __restrict__ wT,
                                               int R, int C) {
  int i = blockIdx.x * 256 + threadIdx.x;
  if (i < R * C) {
    int r = i / C, c = i - r * C;
    wT[(size_t)c * R + r] = f2bf(w[i]);
  }
}

// rel-pos rows packed to bf16: rpb[u][c], u<27: rph, else rpw
__global__ __launch_bounds__(256) void k_cvt_rp(const float* __restrict__ rph,
                                                const float* __restrict__ rpw,
                                                unsigned short* __restrict__ rpb) {
  int i = blockIdx.x * 256 + threadIdx.x;
  if (i < 54 * 64) {
    int u = i >> 6, c = i & 63;
    float v = u < 27 ? rph[u * 64 + c] : rpw[(u - 27) * 64 + c];
    rpb[i] = f2bf(v);
  }
}

// ---------------- GEMM mainloop (m97-style 128x128x32, bf16 MFMA) ----------------
__device__ __forceinline__ void gemm_mainloop(
    const unsigned short* __restrict__ A, const unsigned short* __restrict__ BT,
    int K, int row0, int col0,
    unsigned short* As, unsigned short* Bs, f32x4 acc[4][4]) {
  const int tid = threadIdx.x;
  const int lane = tid & 63, wave = tid >> 6;
  const int lr = lane & 15, lg = lane >> 4;
  const int wm = wave >> 1, wn = wave & 1;
  const int c0 = wave * 2, c1 = c0 + 1;
  const int sr0 = c0 * 16 + (lane >> 2), sr1 = c1 * 16 + (lane >> 2);
  const int scc = (lane & 3) * 8;
  const unsigned short* gA0 = A + (size_t)(row0 + sr0) * K + scc;
  const unsigned short* gA1 = A + (size_t)(row0 + sr1) * K + scc;
  const unsigned short* gB0 = BT + (size_t)(col0 + sr0) * K + scc;
  const unsigned short* gB1 = BT + (size_t)(col0 + sr1) * K + scc;
  unsigned short* lA0 = As + c0 * 512;
  unsigned short* lA1 = As + c1 * 512;
  unsigned short* lB0 = Bs + c0 * 512;
  unsigned short* lB1 = Bs + c1 * 512;
  for (int k0 = 0; k0 < K; k0 += 32) {
    __syncthreads();
    gload16(gA0, lA0); gload16(gA1, lA1);
    gload16(gB0, lB0); gload16(gB1, lB1);
    gA0 += 32; gA1 += 32; gB0 += 32; gB1 += 32;
    __syncthreads();
    bf16x8 af[4], bfr[4];
#pragma unroll
    for (int f = 0; f < 4; f++) {
      af[f]  = *(const bf16x8*)(As + (wm * 64 + f * 16 + lr) * 32 + lg * 8);
      bfr[f] = *(const bf16x8*)(Bs + (wn * 64 + f * 16 + lr) * 32 + lg * 8);
    }
#pragma unroll
    for (int i = 0; i < 4; i++)
#pragma unroll
      for (int j = 0; j < 4; j++)
        acc[i][j] = __builtin_amdgcn_mfma_f32_16x16x32_bf16(af[i], bfr[j], acc[i][j], 0, 0, 0);
  }
}

// GEMM1: qkv = x@w_qkv + b, scattered to planes [3*96][56*56][64] bf16
__global__ __launch_bounds__(256) void k_gemm_qkv(
    const unsigned short* __restrict__ A, const unsigned short* __restrict__ BT,
    const float* __restrict__ bias, unsigned short* __restrict__ qkvp) {
  __shared__ unsigned short As[128 * 32];
  __shared__ unsigned short Bs[128 * 32];
  f32x4 acc[4][4];
  f32x4 z0 = {0.f, 0.f, 0.f, 0.f};
#pragma unroll
  for (int i = 0; i < 4; i++)
#pragma unroll
    for (int j = 0; j < 4; j++) acc[i][j] = z0;
  const int row0 = blockIdx.y * 128, col0 = blockIdx.x * 128;
  gemm_mainloop(A, BT, 768, row0, col0, As, Bs, acc);
  const int lane = threadIdx.x & 63, wave = threadIdx.x >> 6;
  const int lr = lane & 15, lg = lane >> 4;
  const int wm = wave >> 1, wn = wave & 1;
#pragma unroll
  for (int j = 0; j < 4; j++) {
    int col = col0 + wn * 64 + j * 16 + lr;
    float bv = bias[col];
    int qkv_idx = col / 768;
    int head = (col >> 6) % 12;
    int d = col & 63;
#pragma unroll
    for (int i = 0; i < 4; i++) {
#pragma unroll
      for (int r = 0; r < 4; r++) {
        int row = row0 + wm * 64 + i * 16 + lg * 4 + r;
        int b = row / 3136, hw = row - b * 3136;
        size_t dst = (((size_t)(qkv_idx * 96 + b * 12 + head)) * 3136 + hw) * 64 + d;
        qkvp[dst] = f2bf(acc[i][j][r] + bv);
      }
    }
  }
}

// GEMM2: out = X2@w_proj + b (fp32 out, row-major)
__global__ __launch_bounds__(256) void k_gemm_proj(
    const unsigned short* __restrict__ A, const unsigned short* __restrict__ BT,
    const float* __restrict__ bias, float* __restrict__ out) {
  __shared__ unsigned short As[128 * 32];
  __shared__ unsigned short Bs[128 * 32];
  f32x4 acc[4][4];
  f32x4 z0 = {0.f, 0.f, 0.f, 0.f};
#pragma unroll
  for (int i = 0; i < 4; i++)
#pragma unroll
    for (int j = 0; j < 4; j++) acc[i][j] = z0;
  const int row0 = blockIdx.y * 128, col0 = blockIdx.x * 128;
  gemm_mainloop(A, BT, 768, row0, col0, As, Bs, acc);
  const int lane = threadIdx.x & 63, wave = threadIdx.x >> 6;
  const int lr = lane & 15, lg = lane >> 4;
  const int wm = wave >> 1, wn = wave & 1;
#pragma unroll
  for (int j = 0; j < 4; j++) {
    int col = col0 + wn * 64 + j * 16 + lr;
    float bv = bias[col];
#pragma unroll
    for (int i = 0; i < 4; i++) {
#pragma unroll
      for (int r = 0; r < 4; r++) {
        int row = row0 + wm * 64 + i * 16 + lg * 4 + r;
        out[(size_t)row * 768 + col] = acc[i][j][r] + bv;
      }
    }
  }
}

// ---------------- depthwise conv3x3 + LayerNorm, write window layout ----------------
__global__ __launch_bounds__(256) void k_conv_ln(
    const unsigned short* __restrict__ qkvp,
    const float* __restrict__ wq, const float* __restrict__ wk, const float* __restrict__ wv,
    const float* __restrict__ gq, const float* __restrict__ bq,
    const float* __restrict__ gk, const float* __restrict__ bk,
    const float* __restrict__ gv, const float* __restrict__ bv,
    unsigned short* __restrict__ qw_, unsigned short* __restrict__ kw_,
    unsigned short* __restrict__ vw_) {
  int wid = blockIdx.x * 4 + (threadIdx.x >> 6);
  int c = threadIdx.x & 63;
  int plane = wid / 3136;
  int hw = wid - plane * 3136;
  int h = hw / 56, w = hw - (hw / 56) * 56;
  int qkv_idx = plane / 96, p96 = plane - qkv_idx * 96;
  const float* wt = qkv_idx == 0 ? wq : (qkv_idx == 1 ? wk : wv);
  const unsigned short* base = qkvp + (size_t)plane * 3136 * 64;
  float acc = 0.f;
#pragma unroll
  for (int dh = -1; dh <= 1; dh++) {
    int hh = h + dh;
    if ((unsigned)hh < 56u) {
#pragma unroll
      for (int dw = -1; dw <= 1; dw++) {
        int ww = w + dw;
        if ((unsigned)ww < 56u) {
          acc += bf2f(base[(hh * 56 + ww) * 64 + c]) * wt[((dh + 1) * 3 + (dw + 1)) * 64 + c];
        }
      }
    }
  }
  float s = acc;
#pragma unroll
  for (int m = 1; m < 64; m <<= 1) s += __shfl_xor(s, m, 64);
  float mean = s * (1.f / 64.f);
  float dv = acc - mean;
  float s2 = dv * dv;
#pragma unroll
  for (int m = 1; m < 64; m <<= 1) s2 += __shfl_xor(s2, m, 64);
  float rstd = rsqrtf(s2 * (1.f / 64.f) + EPS_LN);
  const float* g = qkv_idx == 0 ? gq : (qkv_idx == 1 ? gk : gv);
  const float* bb = qkv_idx == 0 ? bq : (qkv_idx == 1 ? bk : bv);
  float val = dv * rstd * g[c] + bb[c];
  int win = p96 * 16 + (h / 14) * 4 + (w / 14);
  int rowL = (h % 14) * 14 + (w % 14);
  unsigned short* dst = qkv_idx == 0 ? qw_ : (qkv_idx == 1 ? kw_ : vw_);
  dst[((size_t)win * 196 + rowL) * 64 + c] = f2bf(val);
}

// ---------------- window attention: swapped-QK, in-register softmax ----------------
__global__ __launch_bounds__(256) void k_attn(
    const unsigned short* __restrict__ qw_, const unsigned short* __restrict__ kw_,
    const unsigned short* __restrict__ vw_, const unsigned short* __restrict__ rpb,
    unsigned short* __restrict__ X2) {
  __shared__ __attribute__((aligned(16))) unsigned short Vt[64 * VSTR];  // [c][key]
  __shared__ __attribute__((aligned(16))) unsigned short Rt[54 * RSTR]; // [u][q] bias table
  const int tid = threadIdx.x;
  const int win = blockIdx.x;
  const size_t woff = (size_t)win * (196 * 64);
  const int lane = tid & 63, wave = tid >> 6;
  const int lr = lane & 15, lg = lane >> 4;

  // ---- stage V transposed (vector global reads, scalar LDS writes) ----
  for (int i = tid; i < 1568; i += 256) {  // 196 keys * 8 c-chunks
    int key = i >> 3, cb = (i & 7) * 8;
    bf16x8 v = *(const bf16x8*)(vw_ + woff + key * 64 + cb);
#pragma unroll
    for (int j = 0; j < 8; j++)
      Vt[(cb + j) * VSTR + key] = (unsigned short)v[j];
  }
  // zero-pad keys 196..231 (PV reads up to key 223)
  for (int i = tid; i < 64 * 36; i += 256) {
    int c = i / 36, key = 196 + (i - (i / 36) * 36);
    Vt[c * VSTR + key] = 0;
  }
  // ---- Rt[u][q] = dot(Q[q], rp[u]) via MFMA: 13 q-tiles x 4 u-tiles ----
  for (int job = wave; job < 52; job += 4) {
    int mt = job >> 2, ut = job & 3;
    int u = ut * 16 + lr; if (u > 53) u = 53;
    int q = mt * 16 + lr; if (q > 195) q = 195;
    bf16x8 a0 = *(const bf16x8*)(rpb + u * 64 + lg * 8);
    bf16x8 a1 = *(const bf16x8*)(rpb + u * 64 + 32 + lg * 8);
    bf16x8 b0 = *(const bf16x8*)(qw_ + woff + q * 64 + lg * 8);
    bf16x8 b1 = *(const bf16x8*)(qw_ + woff + q * 64 + 32 + lg * 8);
    f32x4 z = {0.f, 0.f, 0.f, 0.f};
    z = __builtin_amdgcn_mfma_f32_16x16x32_bf16(a0, b0, z, 0, 0, 0);
    z = __builtin_amdgcn_mfma_f32_16x16x32_bf16(a1, b1, z, 0, 0, 0);
#pragma unroll
    for (int r = 0; r < 4; r++) {
      int uo = ut * 16 + lg * 4 + r;
      if (uo < 54) Rt[uo * RSTR + mt * 16 + lr] = f2bf(z[r]);
    }
  }
  __syncthreads();

  const int addrA = (lr + 32 * (lg & 1)) * 4;
  const int addrB = addrA + 64;
  const bool lglo = lg < 2;
  const float scale = 0.125f;
  const int p96 = win >> 4, widx = win & 15;
  const int wh = widx >> 2, ww = widx & 3;
  const int bb = p96 / 12, head = p96 - (p96 / 12) * 12;

  for (int mt = wave; mt < 13; mt += 4) {
    const int q = mt * 16 + lr;               // this lane's q-row (column of S^T)
    const int qc = q > 195 ? 195 : q;
    bf16x8 qb0 = *(const bf16x8*)(qw_ + woff + qc * 64 + lg * 8);
    bf16x8 qb1 = *(const bf16x8*)(qw_ + woff + qc * 64 + 32 + lg * 8);
    const int qh = q / 14, qx = q - qh * 14;
    const int uh0 = qh + 13;                  // u_h = uh0 - ch
    const int uw0 = 27 + qx + 13;             // u_w = uw0 - cw

    // S^T tiles: z[nt] lane holds S[q=lr][key = nt*16 + lg*4 + r]
    f32x4 z[13];
#pragma unroll
    for (int nt = 0; nt < 13; nt++) {
      int kr = nt * 16 + lr; if (kr > 195) kr = 195;
      bf16x8 ka0 = *(const bf16x8*)(kw_ + woff + kr * 64 + lg * 8);
      bf16x8 ka1 = *(const bf16x8*)(kw_ + woff + kr * 64 + 32 + lg * 8);
      f32x4 zz = {0.f, 0.f, 0.f, 0.f};
      zz = __builtin_amdgcn_mfma_f32_16x16x32_bf16(ka0, qb0, zz, 0, 0, 0);
      zz = __builtin_amdgcn_mfma_f32_16x16x32_bf16(ka1, qb1, zz, 0, 0, 0);
      z[nt] = zz;
    }
    // bias + mask + row max
    float mx = -3e38f;
#pragma unroll
    for (int nt = 0; nt < 13; nt++) {
#pragma unroll
      for (int r = 0; r < 4; r++) {
        int key = nt * 16 + lg * 4 + r;
        float v;
        if (key < 196) {
          int ch = key / 14, cw = key - (key / 14) * 14;
          float bias = bf2f(Rt[(uh0 - ch) * RSTR + q]) + bf2f(Rt[(uw0 - cw) * RSTR + q]);
          v = z[nt][r] * scale + bias;
        } else v = -3e38f;
        z[nt][r] = v;
        mx = fmaxf(mx, v);
      }
    }
    mx = fmaxf(mx, __shfl_xor(mx, 16, 64));
    mx = fmaxf(mx, __shfl_xor(mx, 32, 64));
    float sum = 0.f;
#pragma unroll
    for (int nt = 0; nt < 13; nt++)
#pragma unroll
      for (int r = 0; r < 4; r++) {
        float p = __expf(z[nt][r] - mx);
        z[nt][r] = p;
        sum += p;
      }
    sum += __shfl_xor(sum, 16, 64);
    sum += __shfl_xor(sum, 32, 64);
    float inv = 1.f / sum;
    // pack P to bf16 pairs: pk0 = keys(lg*4+0,+1), pk1 = keys(+2,+3)
    unsigned pk0[13], pk1[13];
#pragma unroll
    for (int nt = 0; nt < 13; nt++) {
      pk0[nt] = cvt_pk_bf16(z[nt][0] * inv, z[nt][1] * inv);
      pk1[nt] = cvt_pk_bf16(z[nt][2] * inv, z[nt][3] * inv);
    }
    // PV: exchange P to A-frag layout via ds_bpermute, MFMA against Vt
    f32x4 o[4];
#pragma unroll
    for (int ct = 0; ct < 4; ct++) o[ct] = (f32x4){0.f, 0.f, 0.f, 0.f};
#pragma unroll
    for (int kt = 0; kt < 7; kt++) {
      unsigned s0 = pk0[2 * kt], s1 = pk1[2 * kt];
      unsigned t0 = (kt < 6) ? pk0[2 * kt + 1] : 0u;
      unsigned t1 = (kt < 6) ? pk1[2 * kt + 1] : 0u;
      unsigned a0 = __builtin_amdgcn_ds_bpermute(addrA, (int)s0);
      unsigned b0 = __builtin_amdgcn_ds_bpermute(addrA, (int)t0);
      unsigned a1 = __builtin_amdgcn_ds_bpermute(addrA, (int)s1);
      unsigned b1 = __builtin_amdgcn_ds_bpermute(addrA, (int)t1);
      unsigned a2 = __builtin_amdgcn_ds_bpermute(addrB, (int)s0);
      unsigned b2 = __builtin_amdgcn_ds_bpermute(addrB, (int)t0);
      unsigned a3 = __builtin_amdgcn_ds_bpermute(addrB, (int)s1);
      unsigned b3 = __builtin_amdgcn_ds_bpermute(addrB, (int)t1);
      union { unsigned u[4]; bf16x8 v; } pa;
      pa.u[0] = lglo ? a0 : b0;
      pa.u[1] = lglo ? a1 : b1;
      pa.u[2] = lglo ? a2 : b2;
      pa.u[3] = lglo ? a3 : b3;
#pragma unroll
      for (int ct = 0; ct < 4; ct++) {
        bf16x8 vb = *(const bf16x8*)(Vt + (ct * 16 + lr) * VSTR + kt * 32 + lg * 8);
        o[ct] = __builtin_amdgcn_mfma_f32_16x16x32_bf16(pa.v, vb, o[ct], 0, 0, 0);
      }
    }
    // epilogue: +residual (ori_q == Q window), write to [25088][768] bf16
#pragma unroll
    for (int ct = 0; ct < 4; ct++) {
      int c = ct * 16 + lr;
#pragma unroll
      for (int r = 0; r < 4; r++) {
        int qq = mt * 16 + lg * 4 + r;
        if (qq < 196) {
          float val = o[ct][r] + bf2f(qw_[woff + qq * 64 + c]);
          int qhh = qq / 14, qxx = qq - (qq / 14) * 14;
          int hh = wh * 14 + qhh, wv = ww * 14 + qxx;
          size_t tok = ((size_t)bb * 56 + hh) * 56 + wv;
          X2[tok * 768 + (size_t)head * 64 + c] = f2bf(val);
        }
      }
    }
  }
}

extern "C" void kernel_launch(void* const* d_in, const int* in_sizes, int n_in,
                              void* d_out, int out_size, void* d_ws, size_t ws_size,
                              hipStream_t stream) {
  const float* x      = (const float*)d_in[0];
  const float* w_qkv  = (const float*)d_in[1];
  const float* b_qkv  = (const float*)d_in[2];
  const float* w_proj = (const float*)d_in[3];
  const float* b_proj = (const float*)d_in[4];
  const float* pqw = (const float*)d_in[5];
  const float* pkw = (const float*)d_in[6];
  const float* pvw = (const float*)d_in[7];
  const float* gq = (const float*)d_in[8];
  const float* bq = (const float*)d_in[9];
  const float* gk = (const float*)d_in[10];
  const float* bk = (const float*)d_in[11];
  const float* gv = (const float*)d_in[12];
  const float* bv = (const float*)d_in[13];
  const float* rph = (const float*)d_in[14];
  const float* rpw = (const float*)d_in[15];
  float* out = (float*)d_out;

  char* ws = (char*)d_ws;
  size_t off = 0;
  auto alloc = [&](size_t bytes) {
    void* p = ws + off;
    off = (off + bytes + 255) & ~(size_t)255;
    return p;
  };
  unsigned short* xb   = (unsigned short*)alloc((size_t)TOKENS * 768 * 2);
  unsigned short* wqT  = (unsigned short*)alloc((size_t)2304 * 768 * 2);
  unsigned short* wpT  = (unsigned short*)alloc((size_t)768 * 768 * 2);
  unsigned short* rpb  = (unsigned short*)alloc((size_t)54 * 64 * 2);
  unsigned short* qkvp = (unsigned short*)alloc((size_t)288 * 3136 * 64 * 2);
  unsigned short* qwin = (unsigned short*)alloc((size_t)1536 * 196 * 64 * 2);
  unsigned short* kwin = (unsigned short*)alloc((size_t)1536 * 196 * 64 * 2);
  unsigned short* vwin = (unsigned short*)alloc((size_t)1536 * 196 * 64 * 2);
  unsigned short* X2 = xb;  // alias: xb dead after GEMM1, X2 written by attention

  k_cvt_x<<<dim3(TOKENS * 768 / 1024), dim3(256), 0, stream>>>(x, xb);
  k_cvt_T<<<dim3((768 * 2304 + 255) / 256), dim3(256), 0, stream>>>(w_qkv, wqT, 768, 2304);
  k_cvt_T<<<dim3((768 * 768 + 255) / 256), dim3(256), 0, stream>>>(w_proj, wpT, 768, 768);
  k_cvt_rp<<<dim3(14), dim3(256), 0, stream>>>(rph, rpw, rpb);
  k_gemm_qkv<<<dim3(18, 196), dim3(256), 0, stream>>>(xb, wqT, b_qkv, qkvp);
  k_conv_ln<<<dim3(288 * 3136 / 4), dim3(256), 0, stream>>>(
      qkvp, pqw, pkw, pvw, gq, bq, gk, bk, gv, bv, qwin, kwin, vwin);
  k_attn<<<dim3(1536), dim3(256), 0, stream>>>(qwin, kwin, vwin, rpb, X2);
  k_gemm_proj<<<dim3(6, 196), dim3(256), 0, stream>>>(X2, wpT, b_proj, out);
}

// Round 5
// 653.103 us; speedup vs baseline: 1.9402x; 1.5792x over previous
//
#include <hip/hip_runtime.h>
#include <stdint.h>

#define TOKENS 25088      // 8*56*56
#define EPS_LN 1e-5f
#define VSTR 232          // Vt stride (elems); 232*2B=464B, 16B-aligned, 2-way-read
#define RSTR 208          // Rt stride (elems) = 13*16 q-columns

typedef __attribute__((ext_vector_type(8))) short bf16x8;
typedef __attribute__((ext_vector_type(4))) float f32x4;

__device__ __forceinline__ unsigned short f2bf(float f) {
  union { float f; unsigned u; } v; v.f = f;
  unsigned r = v.u + 0x7FFFu + ((v.u >> 16) & 1u);
  return (unsigned short)(r >> 16);
}
__device__ __forceinline__ float bf2f(unsigned short h) {
  union { unsigned u; float f; } v; v.u = ((unsigned)h) << 16;
  return v.f;
}
__device__ __forceinline__ unsigned cvt_pk_bf16(float lo, float hi) {
  unsigned r;
  asm("v_cvt_pk_bf16_f32 %0, %1, %2" : "=v"(r) : "v"(lo), "v"(hi));
  return r;
}

__device__ __forceinline__ void gload16(const void* g, void* l) {
  __builtin_amdgcn_global_load_lds(
      (const __attribute__((address_space(1))) void*)g,
      (__attribute__((address_space(3))) void*)l, 16, 0, 0);
}

// ---------------- converts ----------------
__global__ __launch_bounds__(256) void k_cvt_x(const float* __restrict__ x,
                                               unsigned short* __restrict__ xb) {
  int i = (blockIdx.x * 256 + threadIdx.x) * 4;
  float4 v = *(const float4*)(x + i);
  unsigned r0 = (unsigned)f2bf(v.x) | ((unsigned)f2bf(v.y) << 16);
  unsigned r1 = (unsigned)f2bf(v.z) | ((unsigned)f2bf(v.w) << 16);
  uint2 o; o.x = r0; o.y = r1;
  *(uint2*)(xb + i) = o;
}

__global__ __launch_bounds__(256) void k_cvt_T(const float* __restrict__ w,
                                               unsigned short* __restrict__ wT,
                                               int R, int C) {
  int i = blockIdx.x * 256 + threadIdx.x;
  if (i < R * C) {
    int r = i / C, c = i - r * C;
    wT[(size_t)c * R + r] = f2bf(w[i]);
  }
}

// rel-pos rows packed to bf16: rpb[u][c], u<27: rph, else rpw
__global__ __launch_bounds__(256) void k_cvt_rp(const float* __restrict__ rph,
                                                const float* __restrict__ rpw,
                                                unsigned short* __restrict__ rpb) {
  int i = blockIdx.x * 256 + threadIdx.x;
  if (i < 54 * 64) {
    int u = i >> 6, c = i & 63;
    float v = u < 27 ? rph[u * 64 + c] : rpw[(u - 27) * 64 + c];
    rpb[i] = f2bf(v);
  }
}

// ---------------- GEMM mainloop (m97-style 128x128x32, bf16 MFMA) ----------------
__device__ __forceinline__ void gemm_mainloop(
    const unsigned short* __restrict__ A, const unsigned short* __restrict__ BT,
    int K, int row0, int col0,
    unsigned short* As, unsigned short* Bs, f32x4 acc[4][4]) {
  const int tid = threadIdx.x;
  const int lane = tid & 63, wave = tid >> 6;
  const int lr = lane & 15, lg = lane >> 4;
  const int wm = wave >> 1, wn = wave & 1;
  const int c0 = wave * 2, c1 = c0 + 1;
  const int sr0 = c0 * 16 + (lane >> 2), sr1 = c1 * 16 + (lane >> 2);
  const int scc = (lane & 3) * 8;
  const unsigned short* gA0 = A + (size_t)(row0 + sr0) * K + scc;
  const unsigned short* gA1 = A + (size_t)(row0 + sr1) * K + scc;
  const unsigned short* gB0 = BT + (size_t)(col0 + sr0) * K + scc;
  const unsigned short* gB1 = BT + (size_t)(col0 + sr1) * K + scc;
  unsigned short* lA0 = As + c0 * 512;
  unsigned short* lA1 = As + c1 * 512;
  unsigned short* lB0 = Bs + c0 * 512;
  unsigned short* lB1 = Bs + c1 * 512;
  for (int k0 = 0; k0 < K; k0 += 32) {
    __syncthreads();
    gload16(gA0, lA0); gload16(gA1, lA1);
    gload16(gB0, lB0); gload16(gB1, lB1);
    gA0 += 32; gA1 += 32; gB0 += 32; gB1 += 32;
    __syncthreads();
    bf16x8 af[4], bfr[4];
#pragma unroll
    for (int f = 0; f < 4; f++) {
      af[f]  = *(const bf16x8*)(As + (wm * 64 + f * 16 + lr) * 32 + lg * 8);
      bfr[f] = *(const bf16x8*)(Bs + (wn * 64 + f * 16 + lr) * 32 + lg * 8);
    }
#pragma unroll
    for (int i = 0; i < 4; i++)
#pragma unroll
      for (int j = 0; j < 4; j++)
        acc[i][j] = __builtin_amdgcn_mfma_f32_16x16x32_bf16(af[i], bfr[j], acc[i][j], 0, 0, 0);
  }
}

// GEMM1: qkv = x@w_qkv + b, scattered to planes [3*96][56*56][64] bf16
__global__ __launch_bounds__(256) void k_gemm_qkv(
    const unsigned short* __restrict__ A, const unsigned short* __restrict__ BT,
    const float* __restrict__ bias, unsigned short* __restrict__ qkvp) {
  __shared__ unsigned short As[128 * 32];
  __shared__ unsigned short Bs[128 * 32];
  f32x4 acc[4][4];
  f32x4 z0 = {0.f, 0.f, 0.f, 0.f};
#pragma unroll
  for (int i = 0; i < 4; i++)
#pragma unroll
    for (int j = 0; j < 4; j++) acc[i][j] = z0;
  const int row0 = blockIdx.y * 128, col0 = blockIdx.x * 128;
  gemm_mainloop(A, BT, 768, row0, col0, As, Bs, acc);
  const int lane = threadIdx.x & 63, wave = threadIdx.x >> 6;
  const int lr = lane & 15, lg = lane >> 4;
  const int wm = wave >> 1, wn = wave & 1;
#pragma unroll
  for (int j = 0; j < 4; j++) {
    int col = col0 + wn * 64 + j * 16 + lr;
    float bv = bias[col];
    int qkv_idx = col / 768;
    int head = (col >> 6) % 12;
    int d = col & 63;
#pragma unroll
    for (int i = 0; i < 4; i++) {
#pragma unroll
      for (int r = 0; r < 4; r++) {
        int row = row0 + wm * 64 + i * 16 + lg * 4 + r;
        int b = row / 3136, hw = row - b * 3136;
        size_t dst = (((size_t)(qkv_idx * 96 + b * 12 + head)) * 3136 + hw) * 64 + d;
        qkvp[dst] = f2bf(acc[i][j][r] + bv);
      }
    }
  }
}

// GEMM2: out = X2@w_proj + b (fp32 out, row-major)
__global__ __launch_bounds__(256) void k_gemm_proj(
    const unsigned short* __restrict__ A, const unsigned short* __restrict__ BT,
    const float* __restrict__ bias, float* __restrict__ out) {
  __shared__ unsigned short As[128 * 32];
  __shared__ unsigned short Bs[128 * 32];
  f32x4 acc[4][4];
  f32x4 z0 = {0.f, 0.f, 0.f, 0.f};
#pragma unroll
  for (int i = 0; i < 4; i++)
#pragma unroll
    for (int j = 0; j < 4; j++) acc[i][j] = z0;
  const int row0 = blockIdx.y * 128, col0 = blockIdx.x * 128;
  gemm_mainloop(A, BT, 768, row0, col0, As, Bs, acc);
  const int lane = threadIdx.x & 63, wave = threadIdx.x >> 6;
  const int lr = lane & 15, lg = lane >> 4;
  const int wm = wave >> 1, wn = wave & 1;
#pragma unroll
  for (int j = 0; j < 4; j++) {
    int col = col0 + wn * 64 + j * 16 + lr;
    float bv = bias[col];
#pragma unroll
    for (int i = 0; i < 4; i++) {
#pragma unroll
      for (int r = 0; r < 4; r++) {
        int row = row0 + wm * 64 + i * 16 + lg * 4 + r;
        out[(size_t)row * 768 + col] = acc[i][j][r] + bv;
      }
    }
  }
}

// ---------------- depthwise conv3x3 + LayerNorm (restructured) ----------------
// wave = 2 adjacent output columns (half-waves) x 7 rows, 2 channels/lane (u32)
__global__ __launch_bounds__(256) void k_conv_ln(
    const unsigned short* __restrict__ qkvp,
    const float* __restrict__ wq, const float* __restrict__ wk, const float* __restrict__ wv,
    const float* __restrict__ gq, const float* __restrict__ bq,
    const float* __restrict__ gk, const float* __restrict__ bk,
    const float* __restrict__ gv, const float* __restrict__ bv,
    unsigned short* __restrict__ qw_, unsigned short* __restrict__ kw_,
    unsigned short* __restrict__ vw_) {
  const int tid = threadIdx.x;
  const int wave = tid >> 6, lane = tid & 63;
  const int half = lane >> 5, l5 = lane & 31;
  const int c2 = l5 * 2;
  const int bx = blockIdx.x;
  const int p = bx / 56, rem = bx - p * 56;
  const int strip = rem / 7, cb = rem - strip * 7;   // strip 0..7, cb 0..6
  const int h0 = strip * 7;
  const int w = cb * 8 + wave * 2 + half;            // this half's output column
  const int qkv_idx = p / 96, p96 = p - qkv_idx * 96;
  const float* wt = qkv_idx == 0 ? wq : (qkv_idx == 1 ? wk : wv);
  const float* g = qkv_idx == 0 ? gq : (qkv_idx == 1 ? gk : gv);
  const float* bbp = qkv_idx == 0 ? bq : (qkv_idx == 1 ? bk : bv);

  float wtl[9], wth[9];
#pragma unroll
  for (int j = 0; j < 9; j++) {
    float2 w2 = *(const float2*)(wt + j * 64 + c2);
    wtl[j] = w2.x; wth[j] = w2.y;
  }
  const float2 g2 = *(const float2*)(g + c2);
  const float2 b2 = *(const float2*)(bbp + c2);

  const unsigned short* base = qkvp + (size_t)p * 3136 * 64;

  // 27 u32 loads: rows h0-1..h0+7, cols w-1..w+1 (clamped + zero-masked)
  unsigned xr[9][3];
#pragma unroll
  for (int k = 0; k < 3; k++) {
    int col = w - 1 + k;
    bool cok = (unsigned)col < 56u;
    int cc = cok ? col : 0;
#pragma unroll
    for (int ri = 0; ri < 9; ri++) {
      int r = h0 + ri - 1;
      bool rok = (unsigned)r < 56u;
      int rc = rok ? r : 0;
      unsigned v = *(const unsigned*)(base + ((rc * 56 + cc) * 64 + c2));
      xr[ri][k] = (rok && cok) ? v : 0u;
    }
  }

  float accL[7], accH[7];
#pragma unroll
  for (int t = 0; t < 7; t++) { accL[t] = 0.f; accH[t] = 0.f; }
#pragma unroll
  for (int ri = 0; ri < 9; ri++) {
    float xl[3], xh[3];
#pragma unroll
    for (int k = 0; k < 3; k++) {
      unsigned u = xr[ri][k];
      union { unsigned u; float f; } a, b;
      a.u = u << 16; b.u = u & 0xffff0000u;
      xl[k] = a.f; xh[k] = b.f;
    }
#pragma unroll
    for (int dh = 0; dh < 3; dh++) {
      int t = ri - dh;
      if (t >= 0 && t < 7) {
#pragma unroll
        for (int k = 0; k < 3; k++) {
          accL[t] += xl[k] * wtl[dh * 3 + k];
          accH[t] += xh[k] * wth[dh * 3 + k];
        }
      }
    }
  }

  const int wdiv = w / 14, wmod = w - wdiv * 14;
  const int win = p96 * 16 + (strip >> 1) * 4 + wdiv;
  unsigned short* dstp = qkv_idx == 0 ? qw_ : (qkv_idx == 1 ? kw_ : vw_);
  unsigned* dstw = (unsigned*)(dstp + (size_t)win * 196 * 64);
#pragma unroll
  for (int t = 0; t < 7; t++) {
    float aL = accL[t], aH = accH[t];
    float s = aL + aH;
    float s2 = aL * aL + aH * aH;
#pragma unroll
    for (int m = 1; m < 32; m <<= 1) {
      s += __shfl_xor(s, m, 64);
      s2 += __shfl_xor(s2, m, 64);
    }
    float mean = s * 0.015625f;
    float var = s2 * 0.015625f - mean * mean;
    float rstd = rsqrtf(var + EPS_LN);
    float vl = (aL - mean) * rstd * g2.x + b2.x;
    float vh = (aH - mean) * rstd * g2.y + b2.y;
    int rowL = ((strip & 1) * 7 + t) * 14 + wmod;
    dstw[rowL * 32 + l5] = cvt_pk_bf16(vl, vh);
  }
}

// ---------------- window attention: swapped-QK, in-register softmax ----------------
__global__ __launch_bounds__(256) void k_attn(
    const unsigned short* __restrict__ qw_, const unsigned short* __restrict__ kw_,
    const unsigned short* __restrict__ vw_, const unsigned short* __restrict__ rpb,
    unsigned short* __restrict__ X2) {
  __shared__ __attribute__((aligned(16))) unsigned short Vt[64 * VSTR];  // [c][key]
  __shared__ __attribute__((aligned(16))) unsigned short Rt[54 * RSTR]; // [u][q] bias table
  const int tid = threadIdx.x;
  const int win = blockIdx.x;
  const size_t woff = (size_t)win * (196 * 64);
  const int lane = tid & 63, wave = tid >> 6;
  const int lr = lane & 15, lg = lane >> 4;

  // ---- stage V transposed (vector global reads, scalar LDS writes) ----
  for (int i = tid; i < 1568; i += 256) {  // 196 keys * 8 c-chunks
    int key = i >> 3, cb = (i & 7) * 8;
    bf16x8 v = *(const bf16x8*)(vw_ + woff + key * 64 + cb);
#pragma unroll
    for (int j = 0; j < 8; j++)
      Vt[(cb + j) * VSTR + key] = (unsigned short)v[j];
  }
  // zero-pad keys 196..231 (PV reads up to key 223)
  for (int i = tid; i < 64 * 36; i += 256) {
    int c = i / 36, key = 196 + (i - (i / 36) * 36);
    Vt[c * VSTR + key] = 0;
  }
  // ---- Rt[u][q] = dot(Q[q], rp[u]) via MFMA: 13 q-tiles x 4 u-tiles ----
  for (int job = wave; job < 52; job += 4) {
    int mt = job >> 2, ut = job & 3;
    int u = ut * 16 + lr; if (u > 53) u = 53;
    int q = mt * 16 + lr; if (q > 195) q = 195;
    bf16x8 a0 = *(const bf16x8*)(rpb + u * 64 + lg * 8);
    bf16x8 a1 = *(const bf16x8*)(rpb + u * 64 + 32 + lg * 8);
    bf16x8 b0 = *(const bf16x8*)(qw_ + woff + q * 64 + lg * 8);
    bf16x8 b1 = *(const bf16x8*)(qw_ + woff + q * 64 + 32 + lg * 8);
    f32x4 z = {0.f, 0.f, 0.f, 0.f};
    z = __builtin_amdgcn_mfma_f32_16x16x32_bf16(a0, b0, z, 0, 0, 0);
    z = __builtin_amdgcn_mfma_f32_16x16x32_bf16(a1, b1, z, 0, 0, 0);
#pragma unroll
    for (int r = 0; r < 4; r++) {
      int uo = ut * 16 + lg * 4 + r;
      if (uo < 54) Rt[uo * RSTR + mt * 16 + lr] = f2bf(z[r]);
    }
  }
  __syncthreads();

  const int addrA = (lr + 32 * (lg & 1)) * 4;
  const int addrB = addrA + 64;
  const bool lglo = lg < 2;
  const float scale = 0.125f;
  const int p96 = win >> 4, widx = win & 15;
  const int wh = widx >> 2, ww = widx & 3;
  const int bb = p96 / 12, head = p96 - (p96 / 12) * 12;

  for (int mt = wave; mt < 13; mt += 4) {
    const int q = mt * 16 + lr;               // this lane's q-row (column of S^T)
    const int qc = q > 195 ? 195 : q;
    bf16x8 qb0 = *(const bf16x8*)(qw_ + woff + qc * 64 + lg * 8);
    bf16x8 qb1 = *(const bf16x8*)(qw_ + woff + qc * 64 + 32 + lg * 8);
    const int qh = q / 14, qx = q - qh * 14;
    const int uh0 = qh + 13;                  // u_h = uh0 - ch
    const int uw0 = 27 + qx + 13;             // u_w = uw0 - cw

    // S^T tiles: z[nt] lane holds S[q=lr][key = nt*16 + lg*4 + r]
    f32x4 z[13];
#pragma unroll
    for (int nt = 0; nt < 13; nt++) {
      int kr = nt * 16 + lr; if (kr > 195) kr = 195;
      bf16x8 ka0 = *(const bf16x8*)(kw_ + woff + kr * 64 + lg * 8);
      bf16x8 ka1 = *(const bf16x8*)(kw_ + woff + kr * 64 + 32 + lg * 8);
      f32x4 zz = {0.f, 0.f, 0.f, 0.f};
      zz = __builtin_amdgcn_mfma_f32_16x16x32_bf16(ka0, qb0, zz, 0, 0, 0);
      zz = __builtin_amdgcn_mfma_f32_16x16x32_bf16(ka1, qb1, zz, 0, 0, 0);
      z[nt] = zz;
    }
    // bias + mask + row max
    float mx = -3e38f;
#pragma unroll
    for (int nt = 0; nt < 13; nt++) {
#pragma unroll
      for (int r = 0; r < 4; r++) {
        int key = nt * 16 + lg * 4 + r;
        float v;
        if (key < 196) {
          int ch = key / 14, cw = key - (key / 14) * 14;
          float bias = bf2f(Rt[(uh0 - ch) * RSTR + q]) + bf2f(Rt[(uw0 - cw) * RSTR + q]);
          v = z[nt][r] * scale + bias;
        } else v = -3e38f;
        z[nt][r] = v;
        mx = fmaxf(mx, v);
      }
    }
    mx = fmaxf(mx, __shfl_xor(mx, 16, 64));
    mx = fmaxf(mx, __shfl_xor(mx, 32, 64));
    float sum = 0.f;
#pragma unroll
    for (int nt = 0; nt < 13; nt++)
#pragma unroll
      for (int r = 0; r < 4; r++) {
        float p = __expf(z[nt][r] - mx);
        z[nt][r] = p;
        sum += p;
      }
    sum += __shfl_xor(sum, 16, 64);
    sum += __shfl_xor(sum, 32, 64);
    float inv = 1.f / sum;
    // pack P to bf16 pairs: pk0 = keys(lg*4+0,+1), pk1 = keys(+2,+3)
    unsigned pk0[13], pk1[13];
#pragma unroll
    for (int nt = 0; nt < 13; nt++) {
      pk0[nt] = cvt_pk_bf16(z[nt][0] * inv, z[nt][1] * inv);
      pk1[nt] = cvt_pk_bf16(z[nt][2] * inv, z[nt][3] * inv);
    }
    // PV: exchange P to A-frag layout via ds_bpermute, MFMA against Vt
    f32x4 o[4];
#pragma unroll
    for (int ct = 0; ct < 4; ct++) o[ct] = (f32x4){0.f, 0.f, 0.f, 0.f};
#pragma unroll
    for (int kt = 0; kt < 7; kt++) {
      unsigned s0 = pk0[2 * kt], s1 = pk1[2 * kt];
      unsigned t0 = (kt < 6) ? pk0[2 * kt + 1] : 0u;
      unsigned t1 = (kt < 6) ? pk1[2 * kt + 1] : 0u;
      unsigned a0 = __builtin_amdgcn_ds_bpermute(addrA, (int)s0);
      unsigned b0 = __builtin_amdgcn_ds_bpermute(addrA, (int)t0);
      unsigned a1 = __builtin_amdgcn_ds_bpermute(addrA, (int)s1);
      unsigned b1 = __builtin_amdgcn_ds_bpermute(addrA, (int)t1);
      unsigned a2 = __builtin_amdgcn_ds_bpermute(addrB, (int)s0);
      unsigned b2 = __builtin_amdgcn_ds_bpermute(addrB, (int)t0);
      unsigned a3 = __builtin_amdgcn_ds_bpermute(addrB, (int)s1);
      unsigned b3 = __builtin_amdgcn_ds_bpermute(addrB, (int)t1);
      union { unsigned u[4]; bf16x8 v; } pa;
      pa.u[0] = lglo ? a0 : b0;
      pa.u[1] = lglo ? a1 : b1;
      pa.u[2] = lglo ? a2 : b2;
      pa.u[3] = lglo ? a3 : b3;
#pragma unroll
      for (int ct = 0; ct < 4; ct++) {
        bf16x8 vb = *(const bf16x8*)(Vt + (ct * 16 + lr) * VSTR + kt * 32 + lg * 8);
        o[ct] = __builtin_amdgcn_mfma_f32_16x16x32_bf16(pa.v, vb, o[ct], 0, 0, 0);
      }
    }
    // epilogue: +residual (ori_q == Q window), write to [25088][768] bf16
#pragma unroll
    for (int ct = 0; ct < 4; ct++) {
      int c = ct * 16 + lr;
#pragma unroll
      for (int r = 0; r < 4; r++) {
        int qq = mt * 16 + lg * 4 + r;
        if (qq < 196) {
          float val = o[ct][r] + bf2f(qw_[woff + qq * 64 + c]);
          int qhh = qq / 14, qxx = qq - (qq / 14) * 14;
          int hh = wh * 14 + qhh, wv = ww * 14 + qxx;
          size_t tok = ((size_t)bb * 56 + hh) * 56 + wv;
          X2[tok * 768 + (size_t)head * 64 + c] = f2bf(val);
        }
      }
    }
  }
}

extern "C" void kernel_launch(void* const* d_in, const int* in_sizes, int n_in,
                              void* d_out, int out_size, void* d_ws, size_t ws_size,
                              hipStream_t stream) {
  const float* x      = (const float*)d_in[0];
  const float* w_qkv  = (const float*)d_in[1];
  const float* b_qkv  = (const float*)d_in[2];
  const float* w_proj = (const float*)d_in[3];
  const float* b_proj = (const float*)d_in[4];
  const float* pqw = (const float*)d_in[5];
  const float* pkw = (const float*)d_in[6];
  const float* pvw = (const float*)d_in[7];
  const float* gq = (const float*)d_in[8];
  const float* bq = (const float*)d_in[9];
  const float* gk = (const float*)d_in[10];
  const float* bk = (const float*)d_in[11];
  const float* gv = (const float*)d_in[12];
  const float* bv = (const float*)d_in[13];
  const float* rph = (const float*)d_in[14];
  const float* rpw = (const float*)d_in[15];
  float* out = (float*)d_out;

  char* ws = (char*)d_ws;
  size_t off = 0;
  auto alloc = [&](size_t bytes) {
    void* p = ws + off;
    off = (off + bytes + 255) & ~(size_t)255;
    return p;
  };
  unsigned short* xb   = (unsigned short*)alloc((size_t)TOKENS * 768 * 2);
  unsigned short* wqT  = (unsigned short*)alloc((size_t)2304 * 768 * 2);
  unsigned short* wpT  = (unsigned short*)alloc((size_t)768 * 768 * 2);
  unsigned short* rpb  = (unsigned short*)alloc((size_t)54 * 64 * 2);
  unsigned short* qkvp = (unsigned short*)alloc((size_t)288 * 3136 * 64 * 2);
  unsigned short* qwin = (unsigned short*)alloc((size_t)1536 * 196 * 64 * 2);
  unsigned short* kwin = (unsigned short*)alloc((size_t)1536 * 196 * 64 * 2);
  unsigned short* vwin = (unsigned short*)alloc((size_t)1536 * 196 * 64 * 2);
  unsigned short* X2 = xb;  // alias: xb dead after GEMM1, X2 written by attention

  k_cvt_x<<<dim3(TOKENS * 768 / 1024), dim3(256), 0, stream>>>(x, xb);
  k_cvt_T<<<dim3((768 * 2304 + 255) / 256), dim3(256), 0, stream>>>(w_qkv, wqT, 768, 2304);
  k_cvt_T<<<dim3((768 * 768 + 255) / 256), dim3(256), 0, stream>>>(w_proj, wpT, 768, 768);
  k_cvt_rp<<<dim3(14), dim3(256), 0, stream>>>(rph, rpw, rpb);
  k_gemm_qkv<<<dim3(18, 196), dim3(256), 0, stream>>>(xb, wqT, b_qkv, qkvp);
  k_conv_ln<<<dim3(288 * 56), dim3(256), 0, stream>>>(
      qkvp, pqw, pkw, pvw, gq, bq, gk, bk, gv, bv, qwin, kwin, vwin);
  k_attn<<<dim3(1536), dim3(256), 0, stream>>>(qwin, kwin, vwin, rpb, X2);
  k_gemm_proj<<<dim3(6, 196), dim3(256), 0, stream>>>(X2, wpT, b_proj, out);
}